// Round 3
// baseline (1072.961 us; speedup 1.0000x reference)
//
#include <hip/hip_runtime.h>

constexpr int H    = 128;
constexpr int NN   = 10000;
constexpr int EE   = 160000;
constexpr int RCN  = 4;      // R*C
constexpr int NG   = 64;     // graphs per replica
constexpr int OUTF = 64;
constexpr int DSEG = 256;    // RCN*NG
constexpr int LDA  = 132;    // padded LDS row stride (floats) for A tiles

__device__ __forceinline__ float gelu_f(float x){
  return 0.5f*x*(1.0f + erff(x*0.70710678118654752440f));
}

// acc[j] += sum_kk a[kk]*w[kk][j]   (same expression shape as round-2 kernel)
__device__ __forceinline__ void fma4(float acc[4], float4 a, const float4 w[4]){
  acc[0] += a.x*w[0].x + a.y*w[1].x + a.z*w[2].x + a.w*w[3].x;
  acc[1] += a.x*w[0].y + a.y*w[1].y + a.z*w[2].y + a.w*w[3].y;
  acc[2] += a.x*w[0].z + a.y*w[1].z + a.z*w[2].z + a.w*w[3].z;
  acc[3] += a.x*w[0].w + a.y*w[1].w + a.z*w[2].w + a.w*w[3].w;
}

// ---------- edge mask
__global__ void k_edge_mask(const int* __restrict__ src, const int* __restrict__ dst,
                            const float* __restrict__ nm, float4* __restrict__ em4){
  int e = blockIdx.x*256 + threadIdx.x;
  if(e >= EE) return;
  int s = src[e], d = dst[e];
  float4 m;
  m.x = nm[0*NN+s]*nm[0*NN+d];
  m.y = nm[1*NN+s]*nm[1*NN+d];
  m.z = nm[2*NN+s]*nm[2*NN+d];
  m.w = nm[3*NN+s]*nm[3*NN+d];
  em4[e] = m;
}

// ---------- CSR build
__global__ void k_hist(const int* __restrict__ dst, int* __restrict__ cnt){
  int e = blockIdx.x*256 + threadIdx.x;
  if(e < EE) atomicAdd(&cnt[dst[e]], 1);
}

__global__ __launch_bounds__(1024) void k_scan(const int* __restrict__ cnt,
                                               int* __restrict__ rs, int* __restrict__ cur){
  __shared__ int part[1024];
  int t = threadIdx.x;
  const int CH = 10;
  int base = t*CH;
  int s = 0;
  #pragma unroll
  for(int j=0;j<CH;j++){ int i = base+j; if(i<NN) s += cnt[i]; }
  part[t] = s;
  __syncthreads();
  for(int off=1; off<1024; off<<=1){
    int v = (t>=off) ? part[t-off] : 0;
    __syncthreads();
    part[t] += v;
    __syncthreads();
  }
  int run = (t==0) ? 0 : part[t-1];
  #pragma unroll
  for(int j=0;j<CH;j++){
    int i = base+j;
    if(i<NN){ rs[i] = run; cur[i] = run; run += cnt[i]; }
  }
  if(t == 1023) rs[NN] = part[1023];
}

__global__ void k_fill(const int* __restrict__ dst,
                       int* __restrict__ cur, int* __restrict__ eid){
  int e = blockIdx.x*256 + threadIdx.x;
  if(e >= EE) return;
  int p = atomicAdd(&cur[dst[e]], 1);
  eid[p] = e;
}

__global__ void k_sortcsr(const int* __restrict__ rs, int* __restrict__ eid,
                          const int* __restrict__ src, int* __restrict__ esrc){
  int n = blockIdx.x*256 + threadIdx.x;
  if(n >= NN) return;
  int jb = rs[n], je = rs[n+1];
  for(int j=jb+1; j<je; j++){
    int v = eid[j];
    int k = j-1;
    while(k >= jb && eid[k] > v){ eid[k+1] = eid[k]; k--; }
    eid[k+1] = v;
  }
  for(int j=jb; j<je; j++) esrc[j] = src[eid[j]];
}

__global__ void k_gbounds(const int* __restrict__ batch, int* __restrict__ gs){
  int g = threadIdx.x;
  if(g > NG) return;
  if(g == NG){ gs[NG] = NN; return; }
  int lo = 0, hi = NN;
  while(lo < hi){
    int mid = (lo+hi)>>1;
    if(batch[mid] < g) lo = mid+1; else hi = mid;
  }
  gs[g] = lo;
}

// ---------- emb = edge_attr @ W + b : 128x128 tile, 256 thr, 8x8 per thread
__global__ __launch_bounds__(256) void k_emb(const float* __restrict__ A, const float* __restrict__ W,
                       const float* __restrict__ bias, float* __restrict__ emb){
  __shared__ float Al[128*LDA];  // 66 KB (padded)
  __shared__ float Wl[H*H];      // 64 KB
  int t = threadIdx.x;
  {
    const float4* a4 = (const float4*)(A + (size_t)blockIdx.x*128*H);
    const float4* w4 = (const float4*)W;
    float4* wl4 = (float4*)Wl;
    #pragma unroll
    for(int i=0;i<16;i++){
      int idx = t + i*256;
      wl4[idx] = w4[idx];
      int r = idx >> 5, c4 = idx & 31;
      *(float4*)&Al[r*LDA + c4*4] = a4[idx];
    }
  }
  __syncthreads();
  int tx = t & 15, ty = t >> 4;
  int c0 = tx*4, c1 = c0 + 64;
  int r0 = ty*4, r1 = r0 + 64;
  float acc[2][2][4][4] = {};
  #pragma unroll 2
  for(int k=0;k<H;k+=4){
    float4 wA[4], wB[4];
    #pragma unroll
    for(int kk=0;kk<4;kk++){
      wA[kk] = *(const float4*)&Wl[(k+kk)*H + c0];
      wB[kk] = *(const float4*)&Wl[(k+kk)*H + c1];
    }
    float4 aA[4], aB[4];
    #pragma unroll
    for(int i=0;i<4;i++){
      aA[i] = *(const float4*)&Al[(r0+i)*LDA + k];
      aB[i] = *(const float4*)&Al[(r1+i)*LDA + k];
    }
    #pragma unroll
    for(int i=0;i<4;i++){
      fma4(acc[0][0][i], aA[i], wA);
      fma4(acc[0][1][i], aA[i], wB);
      fma4(acc[1][0][i], aB[i], wA);
      fma4(acc[1][1][i], aB[i], wB);
    }
  }
  float4 bv0 = *(const float4*)&bias[c0];
  float4 bv1 = *(const float4*)&bias[c1];
  float* ob = emb + (size_t)blockIdx.x*128*H;
  #pragma unroll
  for(int i=0;i<4;i++){
    float4 o;
    o.x=acc[0][0][i][0]+bv0.x; o.y=acc[0][0][i][1]+bv0.y; o.z=acc[0][0][i][2]+bv0.z; o.w=acc[0][0][i][3]+bv0.w;
    *(float4*)&ob[(r0+i)*H + c0] = o;
    o.x=acc[0][1][i][0]+bv1.x; o.y=acc[0][1][i][1]+bv1.y; o.z=acc[0][1][i][2]+bv1.z; o.w=acc[0][1][i][3]+bv1.w;
    *(float4*)&ob[(r0+i)*H + c1] = o;
    o.x=acc[1][0][i][0]+bv0.x; o.y=acc[1][0][i][1]+bv0.y; o.z=acc[1][0][i][2]+bv0.z; o.w=acc[1][0][i][3]+bv0.w;
    *(float4*)&ob[(r1+i)*H + c0] = o;
    o.x=acc[1][1][i][0]+bv1.x; o.y=acc[1][1][i][1]+bv1.y; o.z=acc[1][1][i][2]+bv1.z; o.w=acc[1][1][i][3]+bv1.w;
    *(float4*)&ob[(r1+i)*H + c1] = o;
  }
}

// ---------- aggregation: one wave per node; lane half selects rc pair
template<bool FIRST>
__global__ __launch_bounds__(256) void k_agg(const float* __restrict__ hin, const float* __restrict__ emb,
                       const float4* __restrict__ em4, const int* __restrict__ rs,
                       const int* __restrict__ eid, const int* __restrict__ esrc,
                       const float* __restrict__ epsp, float* __restrict__ tout){
  int t = threadIdx.x;
  int w = t >> 6;              // wave 0..3
  int lane = t & 63;
  int half = lane >> 5;        // 0: rc 0,1   1: rc 2,3
  int l32 = lane & 31;
  int n = blockIdx.x*4 + w;
  int d0 = l32*4;
  int rc0 = half*2, rc1 = rc0+1;
  float4 acc0 = {0.f,0.f,0.f,0.f}, acc1 = {0.f,0.f,0.f,0.f};
  int jb = rs[n], je = rs[n+1];
  for(int j=jb; j<je; j++){
    int e = eid[j], s = esrc[j];
    float4 ev = *(const float4*)&emb[(size_t)e*H + d0];
    float4 m  = em4[e];
    float m0 = half ? m.z : m.x;
    float m1 = half ? m.w : m.y;
    if(FIRST){
      float4 xv = *(const float4*)&hin[(size_t)s*H + d0];
      float gx = gelu_f(xv.x+ev.x);
      float gy = gelu_f(xv.y+ev.y);
      float gz = gelu_f(xv.z+ev.z);
      float gw = gelu_f(xv.w+ev.w);
      acc0.x += gx*m0; acc0.y += gy*m0; acc0.z += gz*m0; acc0.w += gw*m0;
      acc1.x += gx*m1; acc1.y += gy*m1; acc1.z += gz*m1; acc1.w += gw*m1;
    } else {
      float4 h0 = *(const float4*)&hin[((size_t)rc0*NN + s)*H + d0];
      float4 h1 = *(const float4*)&hin[((size_t)rc1*NN + s)*H + d0];
      acc0.x += gelu_f(h0.x+ev.x)*m0;
      acc0.y += gelu_f(h0.y+ev.y)*m0;
      acc0.z += gelu_f(h0.z+ev.z)*m0;
      acc0.w += gelu_f(h0.w+ev.w)*m0;
      acc1.x += gelu_f(h1.x+ev.x)*m1;
      acc1.y += gelu_f(h1.y+ev.y)*m1;
      acc1.z += gelu_f(h1.z+ev.z)*m1;
      acc1.w += gelu_f(h1.w+ev.w)*m1;
    }
  }
  float e1 = 1.0f + epsp[0];
  {
    const float* hb = FIRST ? (hin + (size_t)n*H) : (hin + ((size_t)rc0*NN + n)*H);
    float4 hv = *(const float4*)&hb[d0];
    float4 o;
    o.x = e1*hv.x + acc0.x; o.y = e1*hv.y + acc0.y;
    o.z = e1*hv.z + acc0.z; o.w = e1*hv.w + acc0.w;
    *(float4*)&tout[((size_t)rc0*NN + n)*H + d0] = o;
  }
  {
    const float* hb = FIRST ? (hin + (size_t)n*H) : (hin + ((size_t)rc1*NN + n)*H);
    float4 hv = *(const float4*)&hb[d0];
    float4 o;
    o.x = e1*hv.x + acc1.x; o.y = e1*hv.y + acc1.y;
    o.z = e1*hv.z + acc1.z; o.w = e1*hv.w + acc1.w;
    *(float4*)&tout[((size_t)rc1*NN + n)*H + d0] = o;
  }
}

// ---------- conv: h = gelu(gelu(t@W1+b1)@W2+b2), 128-row tiles, fused
__global__ __launch_bounds__(256) void k_conv(const float* __restrict__ T, const float* __restrict__ W1,
                        const float* __restrict__ b1, const float* __restrict__ W2,
                        const float* __restrict__ b2, float* __restrict__ Ho, int nrows){
  __shared__ float Al[128*LDA];
  __shared__ float Wl[H*H];
  int t = threadIdx.x;
  int rowbase = blockIdx.x*128;
  {
    const float4* w4 = (const float4*)W1;
    float4* wl4 = (float4*)Wl;
    #pragma unroll
    for(int i=0;i<16;i++){
      int idx = t + i*256;
      wl4[idx] = w4[idx];
      int r = idx >> 5, c4 = idx & 31;
      int gr = rowbase + r;
      float4 v = {0.f,0.f,0.f,0.f};
      if(gr < nrows) v = *(const float4*)&T[(size_t)gr*H + c4*4];
      *(float4*)&Al[r*LDA + c4*4] = v;
    }
  }
  __syncthreads();
  int tx = t & 15, ty = t >> 4;
  int c0 = tx*4, c1 = c0 + 64;
  int r0 = ty*4, r1 = r0 + 64;
  float acc[2][2][4][4] = {};
  #pragma unroll 2
  for(int k=0;k<H;k+=4){
    float4 wA[4], wB[4];
    #pragma unroll
    for(int kk=0;kk<4;kk++){
      wA[kk] = *(const float4*)&Wl[(k+kk)*H + c0];
      wB[kk] = *(const float4*)&Wl[(k+kk)*H + c1];
    }
    float4 aA[4], aB[4];
    #pragma unroll
    for(int i=0;i<4;i++){
      aA[i] = *(const float4*)&Al[(r0+i)*LDA + k];
      aB[i] = *(const float4*)&Al[(r1+i)*LDA + k];
    }
    #pragma unroll
    for(int i=0;i<4;i++){
      fma4(acc[0][0][i], aA[i], wA);
      fma4(acc[0][1][i], aA[i], wB);
      fma4(acc[1][0][i], aB[i], wA);
      fma4(acc[1][1][i], aB[i], wB);
    }
  }
  float4 bv0 = *(const float4*)&b1[c0];
  float4 bv1 = *(const float4*)&b1[c1];
  __syncthreads();   // all GEMM1 reads of Al/Wl complete
  // write u into Al; stage W2 into Wl
  #pragma unroll
  for(int i=0;i<4;i++){
    float4 o;
    o.x=gelu_f(acc[0][0][i][0]+bv0.x); o.y=gelu_f(acc[0][0][i][1]+bv0.y);
    o.z=gelu_f(acc[0][0][i][2]+bv0.z); o.w=gelu_f(acc[0][0][i][3]+bv0.w);
    *(float4*)&Al[(r0+i)*LDA + c0] = o;
    o.x=gelu_f(acc[0][1][i][0]+bv1.x); o.y=gelu_f(acc[0][1][i][1]+bv1.y);
    o.z=gelu_f(acc[0][1][i][2]+bv1.z); o.w=gelu_f(acc[0][1][i][3]+bv1.w);
    *(float4*)&Al[(r0+i)*LDA + c1] = o;
    o.x=gelu_f(acc[1][0][i][0]+bv0.x); o.y=gelu_f(acc[1][0][i][1]+bv0.y);
    o.z=gelu_f(acc[1][0][i][2]+bv0.z); o.w=gelu_f(acc[1][0][i][3]+bv0.w);
    *(float4*)&Al[(r1+i)*LDA + c0] = o;
    o.x=gelu_f(acc[1][1][i][0]+bv1.x); o.y=gelu_f(acc[1][1][i][1]+bv1.y);
    o.z=gelu_f(acc[1][1][i][2]+bv1.z); o.w=gelu_f(acc[1][1][i][3]+bv1.w);
    *(float4*)&Al[(r1+i)*LDA + c1] = o;
  }
  {
    const float4* w4 = (const float4*)W2;
    float4* wl4 = (float4*)Wl;
    #pragma unroll
    for(int i=0;i<16;i++) wl4[t+i*256] = w4[t+i*256];
  }
  __syncthreads();
  float acc2[2][2][4][4] = {};
  #pragma unroll 2
  for(int k=0;k<H;k+=4){
    float4 wA[4], wB[4];
    #pragma unroll
    for(int kk=0;kk<4;kk++){
      wA[kk] = *(const float4*)&Wl[(k+kk)*H + c0];
      wB[kk] = *(const float4*)&Wl[(k+kk)*H + c1];
    }
    float4 aA[4], aB[4];
    #pragma unroll
    for(int i=0;i<4;i++){
      aA[i] = *(const float4*)&Al[(r0+i)*LDA + k];
      aB[i] = *(const float4*)&Al[(r1+i)*LDA + k];
    }
    #pragma unroll
    for(int i=0;i<4;i++){
      fma4(acc2[0][0][i], aA[i], wA);
      fma4(acc2[0][1][i], aA[i], wB);
      fma4(acc2[1][0][i], aB[i], wA);
      fma4(acc2[1][1][i], aB[i], wB);
    }
  }
  float4 c2v0 = *(const float4*)&b2[c0];
  float4 c2v1 = *(const float4*)&b2[c1];
  #pragma unroll
  for(int i=0;i<4;i++){
    int gr0 = rowbase + r0 + i, gr1 = rowbase + r1 + i;
    float4 o;
    if(gr0 < nrows){
      o.x=gelu_f(acc2[0][0][i][0]+c2v0.x); o.y=gelu_f(acc2[0][0][i][1]+c2v0.y);
      o.z=gelu_f(acc2[0][0][i][2]+c2v0.z); o.w=gelu_f(acc2[0][0][i][3]+c2v0.w);
      *(float4*)&Ho[(size_t)gr0*H + c0] = o;
      o.x=gelu_f(acc2[0][1][i][0]+c2v1.x); o.y=gelu_f(acc2[0][1][i][1]+c2v1.y);
      o.z=gelu_f(acc2[0][1][i][2]+c2v1.z); o.w=gelu_f(acc2[0][1][i][3]+c2v1.w);
      *(float4*)&Ho[(size_t)gr0*H + c1] = o;
    }
    if(gr1 < nrows){
      o.x=gelu_f(acc2[1][0][i][0]+c2v0.x); o.y=gelu_f(acc2[1][0][i][1]+c2v0.y);
      o.z=gelu_f(acc2[1][0][i][2]+c2v0.z); o.w=gelu_f(acc2[1][0][i][3]+c2v0.w);
      *(float4*)&Ho[(size_t)gr1*H + c0] = o;
      o.x=gelu_f(acc2[1][1][i][0]+c2v1.x); o.y=gelu_f(acc2[1][1][i][1]+c2v1.y);
      o.z=gelu_f(acc2[1][1][i][2]+c2v1.z); o.w=gelu_f(acc2[1][1][i][3]+c2v1.w);
      *(float4*)&Ho[(size_t)gr1*H + c1] = o;
    }
  }
}

// ---------- final MLP: y = gelu(h@W1+b1)@W2+b2   (128-row tiles)
__global__ __launch_bounds__(256) void k_mlp(const float* __restrict__ Hf, const float* __restrict__ W1,
     const float* __restrict__ b1, const float* __restrict__ W2, const float* __restrict__ b2,
     float* __restrict__ y, int nrows){
  __shared__ float Al[128*LDA];
  __shared__ float Wl[H*H];
  int t = threadIdx.x;
  int rowbase = blockIdx.x*128;
  {
    const float4* w4 = (const float4*)W1;
    float4* wl4 = (float4*)Wl;
    #pragma unroll
    for(int i=0;i<16;i++){
      int idx = t + i*256;
      wl4[idx] = w4[idx];
      int r = idx >> 5, c4 = idx & 31;
      int gr = rowbase + r;
      float4 v = {0.f,0.f,0.f,0.f};
      if(gr < nrows) v = *(const float4*)&Hf[(size_t)gr*H + c4*4];
      *(float4*)&Al[r*LDA + c4*4] = v;
    }
  }
  __syncthreads();
  int tx = t & 15, ty = t >> 4;
  int c0 = tx*4, c1 = c0 + 64;
  int r0 = ty*4, r1 = r0 + 64;
  float acc[2][2][4][4] = {};
  #pragma unroll 2
  for(int k=0;k<H;k+=4){
    float4 wA[4], wB[4];
    #pragma unroll
    for(int kk=0;kk<4;kk++){
      wA[kk] = *(const float4*)&Wl[(k+kk)*H + c0];
      wB[kk] = *(const float4*)&Wl[(k+kk)*H + c1];
    }
    float4 aA[4], aB[4];
    #pragma unroll
    for(int i=0;i<4;i++){
      aA[i] = *(const float4*)&Al[(r0+i)*LDA + k];
      aB[i] = *(const float4*)&Al[(r1+i)*LDA + k];
    }
    #pragma unroll
    for(int i=0;i<4;i++){
      fma4(acc[0][0][i], aA[i], wA);
      fma4(acc[0][1][i], aA[i], wB);
      fma4(acc[1][0][i], aB[i], wA);
      fma4(acc[1][1][i], aB[i], wB);
    }
  }
  float4 bv0 = *(const float4*)&b1[c0];
  float4 bv1 = *(const float4*)&b1[c1];
  __syncthreads();
  #pragma unroll
  for(int i=0;i<4;i++){
    float4 o;
    o.x=gelu_f(acc[0][0][i][0]+bv0.x); o.y=gelu_f(acc[0][0][i][1]+bv0.y);
    o.z=gelu_f(acc[0][0][i][2]+bv0.z); o.w=gelu_f(acc[0][0][i][3]+bv0.w);
    *(float4*)&Al[(r0+i)*LDA + c0] = o;
    o.x=gelu_f(acc[0][1][i][0]+bv1.x); o.y=gelu_f(acc[0][1][i][1]+bv1.y);
    o.z=gelu_f(acc[0][1][i][2]+bv1.z); o.w=gelu_f(acc[0][1][i][3]+bv1.w);
    *(float4*)&Al[(r0+i)*LDA + c1] = o;
    o.x=gelu_f(acc[1][0][i][0]+bv0.x); o.y=gelu_f(acc[1][0][i][1]+bv0.y);
    o.z=gelu_f(acc[1][0][i][2]+bv0.z); o.w=gelu_f(acc[1][0][i][3]+bv0.w);
    *(float4*)&Al[(r1+i)*LDA + c0] = o;
    o.x=gelu_f(acc[1][1][i][0]+bv1.x); o.y=gelu_f(acc[1][1][i][1]+bv1.y);
    o.z=gelu_f(acc[1][1][i][2]+bv1.z); o.w=gelu_f(acc[1][1][i][3]+bv1.w);
    *(float4*)&Al[(r1+i)*LDA + c1] = o;
  }
  {
    const float4* w4 = (const float4*)W2;   // 128x64
    float4* wl4 = (float4*)Wl;
    #pragma unroll
    for(int i=0;i<8;i++) wl4[t+i*256] = w4[t+i*256];
  }
  __syncthreads();
  // GEMM2: 128 rows x 64 cols; thread = 8 rows x 4 cols
  int tx2 = t & 15, ty2 = t >> 4;
  int c2 = tx2*4;
  int rr = ty2*8;
  float a2[8][4] = {};
  #pragma unroll 2
  for(int k=0;k<H;k+=4){
    float4 wv[4];
    #pragma unroll
    for(int kk=0;kk<4;kk++) wv[kk] = *(const float4*)&Wl[(k+kk)*OUTF + c2];
    #pragma unroll
    for(int i=0;i<8;i++){
      float4 a = *(const float4*)&Al[(rr+i)*LDA + k];
      fma4(a2[i], a, wv);
    }
  }
  float4 b2v = *(const float4*)&b2[c2];
  #pragma unroll
  for(int i=0;i<8;i++){
    int gr = rowbase + rr + i;
    if(gr < nrows){
      float4 o;
      o.x = a2[i][0]+b2v.x; o.y = a2[i][1]+b2v.y;
      o.z = a2[i][2]+b2v.z; o.w = a2[i][3]+b2v.w;
      *(float4*)&y[(size_t)gr*OUTF + c2] = o;
    }
  }
}

// ---------- deterministic masked segment mean
__global__ __launch_bounds__(64) void k_pool(const float* __restrict__ y, const float* __restrict__ nm,
                       const int* __restrict__ gs, float* __restrict__ out){
  int seg = blockIdx.x;
  int rc = seg / NG;
  int g  = seg - rc*NG;
  int c  = threadIdx.x;
  int nb = gs[g], ne = gs[g+1];
  float num = 0.f, den = 0.f;
  for(int n=nb; n<ne; n++){
    float w = nm[rc*NN + n];
    num += y[((size_t)rc*NN + n)*OUTF + c] * w;
    den += w;
  }
  out[seg*OUTF + c] = num / fmaxf(den, 1e-12f);
}

extern "C" void kernel_launch(void* const* d_in, const int* in_sizes, int n_in,
                              void* d_out, int out_size, void* d_ws, size_t ws_size,
                              hipStream_t stream){
  const float* x         = (const float*)d_in[0];
  const float* edge_attr = (const float*)d_in[1];
  const float* node_mask = (const float*)d_in[2];
  const float* bond_W    = (const float*)d_in[3];
  const float* bond_b    = (const float*)d_in[4];
  const float* epsv      = (const float*)d_in[5];
  const float* conv_W1   = (const float*)d_in[6];
  const float* conv_b1   = (const float*)d_in[7];
  const float* conv_W2   = (const float*)d_in[8];
  const float* conv_b2   = (const float*)d_in[9];
  const float* mlp_W1    = (const float*)d_in[10];
  const float* mlp_b1    = (const float*)d_in[11];
  const float* mlp_W2    = (const float*)d_in[12];
  const float* mlp_b2    = (const float*)d_in[13];
  const int*   eidx      = (const int*)d_in[14];
  const int*   batch     = (const int*)d_in[15];
  const int* srcp = eidx;
  const int* dstp = eidx + EE;

  char* p = (char*)d_ws;
  auto alloc = [&](size_t bytes)->char*{
    char* r = p; p += (bytes + 255) & ~size_t(255); return r;
  };
  float*  h    = (float*) alloc((size_t)RCN*NN*H*4);
  float*  tbuf = (float*) alloc((size_t)RCN*NN*H*4);
  float*  emb  = (float*) alloc((size_t)EE*H*4);
  float4* em4  = (float4*)alloc((size_t)EE*16);
  float*  y    = (float*) alloc((size_t)RCN*NN*OUTF*4);
  int*    cnt  = (int*)   alloc((size_t)NN*4);
  int*    rs   = (int*)   alloc((size_t)(NN+1)*4);
  int*    cur  = (int*)   alloc((size_t)NN*4);
  int*    eid  = (int*)   alloc((size_t)EE*4);
  int*    esrc = (int*)   alloc((size_t)EE*4);
  int*    gs   = (int*)   alloc((size_t)(NG+1)*4);
  if((size_t)(p - (char*)d_ws) > ws_size) return;

  hipMemsetAsync(cnt, 0, (size_t)NN*4, stream);

  k_edge_mask<<<(EE+255)/256, 256, 0, stream>>>(srcp, dstp, node_mask, em4);
  k_hist     <<<(EE+255)/256, 256, 0, stream>>>(dstp, cnt);
  k_scan     <<<1, 1024, 0, stream>>>(cnt, rs, cur);
  k_fill     <<<(EE+255)/256, 256, 0, stream>>>(dstp, cur, eid);
  k_sortcsr  <<<(NN+255)/256, 256, 0, stream>>>(rs, eid, srcp, esrc);
  k_gbounds  <<<1, 128, 0, stream>>>(batch, gs);

  const int NROWS = RCN*NN;
  for(int l=0; l<3; l++){
    k_emb<<<EE/128, 256, 0, stream>>>(edge_attr, bond_W + (size_t)l*H*H, bond_b + l*H, emb);
    if(l == 0)
      k_agg<true ><<<NN/4, 256, 0, stream>>>(x, emb, em4, rs, eid, esrc, epsv + l, tbuf);
    else
      k_agg<false><<<NN/4, 256, 0, stream>>>(h, emb, em4, rs, eid, esrc, epsv + l, tbuf);
    k_conv<<<(NROWS+127)/128, 256, 0, stream>>>(tbuf, conv_W1 + (size_t)l*H*H, conv_b1 + l*H,
                                                conv_W2 + (size_t)l*H*H, conv_b2 + l*H, h, NROWS);
  }
  k_mlp<<<(NROWS+127)/128, 256, 0, stream>>>(h, mlp_W1, mlp_b1, mlp_W2, mlp_b2, y, NROWS);
  k_pool<<<DSEG, 64, 0, stream>>>(y, node_mask, gs, (float*)d_out);
}